// Round 10
// baseline (543.617 us; speedup 1.0000x reference)
//
#include <hip/hip_runtime.h>
#include <hip/hip_bf16.h>

typedef __hip_bfloat16 bf16;
typedef __hip_bfloat162 bf162;

#define NN 100000
#define NE 1600000
#define BN_EPS 1e-5f

// bucketed CSR build
#define BSH 8
#define NBUCK ((NN + 255) >> BSH)      // 391
#define ABLK 128
#define EPBA ((NE + ABLK - 1) / ABLK)  // 12500
#define CAP 6144                       // staging capacity (mean bucket = 4096, sigma ~ 64)

struct alignas(16) bf16x8 { bf16 v[8]; };

typedef __bf16 bfrag __attribute__((ext_vector_type(8)));
typedef float f4 __attribute__((ext_vector_type(4)));
typedef float f2 __attribute__((ext_vector_type(2)));

static __device__ __forceinline__ float b2f(bf16 x){ return __bfloat162float(x); }
static __device__ __forceinline__ bf16 f2b(float x){ return __float2bfloat16(x); }

static __device__ __forceinline__ f2 pkmax0(f2 a) { f2 r; r.x = fmaxf(a.x, 0.f); r.y = fmaxf(a.y, 0.f); return r; }

// pack 8 fp32 -> 8 fp8(e4m3, hw OCP on gfx950) as uint2
static __device__ __forceinline__ uint2 pk8_fp8(float x0,float x1,float x2,float x3,
                                                float x4,float x5,float x6,float x7)
{
    int lo = __builtin_amdgcn_cvt_pk_fp8_f32(x0, x1, 0, 0);
    lo = __builtin_amdgcn_cvt_pk_fp8_f32(x2, x3, lo, 1);
    int hi = __builtin_amdgcn_cvt_pk_fp8_f32(x4, x5, 0, 0);
    hi = __builtin_amdgcn_cvt_pk_fp8_f32(x6, x7, hi, 1);
    return make_uint2((unsigned)lo, (unsigned)hi);
}

// ---------------- fp32 -> bf16 + fp8 convert ----------------
__global__ __launch_bounds__(256) void k_convert(const float* __restrict__ in, bf16* __restrict__ out,
                                                 unsigned char* __restrict__ outf8, int n)
{
    int i = (blockIdx.x * 256 + threadIdx.x) * 8;
    if (i + 7 < n) {
        float4 a = *(const float4*)(in + i);
        float4 b = *(const float4*)(in + i + 4);
        bf16x8 o;
        o.v[0]=f2b(a.x); o.v[1]=f2b(a.y); o.v[2]=f2b(a.z); o.v[3]=f2b(a.w);
        o.v[4]=f2b(b.x); o.v[5]=f2b(b.y); o.v[6]=f2b(b.z); o.v[7]=f2b(b.w);
        *(bf16x8*)(out + i) = o;
        *(uint2*)(outf8 + i) = pk8_fp8(a.x,a.y,a.z,a.w,b.x,b.y,b.z,b.w);
    }
}

// ---------------- weight transpose+convert: Wt[n][k] = bf16(W[k][n]) ----------------
__global__ __launch_bounds__(256) void k_wtrans(const float* __restrict__ W0, const float* __restrict__ W1,
                                                const float* __restrict__ W2, const float* __restrict__ W3,
                                                bf16* __restrict__ T0, bf16* __restrict__ T1,
                                                bf16* __restrict__ T2, bf16* __restrict__ T3)
{
    int m = blockIdx.x >> 6;
    int t = (blockIdx.x & 63) * 256 + threadIdx.x;
    const float* W = (m == 0) ? W0 : (m == 1) ? W1 : (m == 2) ? W2 : W3;
    bf16* T = (m == 0) ? T0 : (m == 1) ? T1 : (m == 2) ? T2 : T3;
    int n = t >> 7, k = t & 127;
    T[n * 128 + k] = f2b(W[k * 128 + n]);
}

// ---------------- pass A1: per-block bucket histograms for BOTH dst and src ----------------
__global__ __launch_bounds__(256) void k_pa1(const int* __restrict__ dst, const int* __restrict__ src,
                                             int* __restrict__ bucketCountD, int* __restrict__ blockBaseD,
                                             int* __restrict__ bucketCountS, int* __restrict__ blockBaseS)
{
    __shared__ int histD[NBUCK];
    __shared__ int histS[NBUCK];
    int t = threadIdx.x;
    for (int i = t; i < NBUCK; i += 256) { histD[i] = 0; histS[i] = 0; }
    __syncthreads();
    int e0 = blockIdx.x * EPBA, e1 = min(e0 + EPBA, NE);
    for (int e = e0 + t; e < e1; e += 256) {
        unsigned bd = ((unsigned)dst[e]) >> BSH;
        unsigned bs = ((unsigned)src[e]) >> BSH;
        if (bd < (unsigned)NBUCK) atomicAdd(&histD[bd], 1);
        if (bs < (unsigned)NBUCK) atomicAdd(&histS[bs], 1);
    }
    __syncthreads();
    for (int i = t; i < NBUCK; i += 256) {
        blockBaseD[blockIdx.x * NBUCK + i] = atomicAdd(&bucketCountD[i], histD[i]);
        blockBaseS[blockIdx.x * NBUCK + i] = atomicAdd(&bucketCountS[i], histS[i]);
    }
}

// ---------------- bucket scan x2 (391 -> exclusive), block 0 = D, block 1 = S ----------------
__global__ __launch_bounds__(512) void k_bscan2(const int* __restrict__ cntD, int* __restrict__ startD,
                                                const int* __restrict__ cntS, int* __restrict__ startS)
{
    __shared__ int sd[512];
    const int* cnt = (blockIdx.x == 0) ? cntD : cntS;
    int* start = (blockIdx.x == 0) ? startD : startS;
    int t = threadIdx.x;
    int v = (t < NBUCK) ? cnt[t] : 0;
    sd[t] = v;
    __syncthreads();
    for (int o = 1; o < 512; o <<= 1) {
        int x = (t >= o) ? sd[t - o] : 0;
        __syncthreads();
        sd[t] += x;
        __syncthreads();
    }
    if (t < NBUCK) start[t] = sd[t] - v;
    if (t == 0) start[NBUCK] = NE;
}

// ---------------- pass A2: scatter pairsD (by dst) + packed packS (by src: (src&255)<<24 | dst) ----------------
__global__ __launch_bounds__(256) void k_pa2(const int* __restrict__ src, const int* __restrict__ dst,
                                             const int* __restrict__ bucketStartD, const int* __restrict__ blockBaseD,
                                             const int* __restrict__ bucketStartS, const int* __restrict__ blockBaseS,
                                             uint2* __restrict__ pairsD, unsigned* __restrict__ packS)
{
    __shared__ int baseD[NBUCK];
    __shared__ int curD[NBUCK];
    __shared__ int baseS[NBUCK];
    __shared__ int curS[NBUCK];
    int t = threadIdx.x;
    for (int i = t; i < NBUCK; i += 256) {
        baseD[i] = bucketStartD[i] + blockBaseD[blockIdx.x * NBUCK + i];
        curD[i] = 0;
        baseS[i] = bucketStartS[i] + blockBaseS[blockIdx.x * NBUCK + i];
        curS[i] = 0;
    }
    __syncthreads();
    int e0 = blockIdx.x * EPBA, e1 = min(e0 + EPBA, NE);
    for (int e = e0 + t; e < e1; e += 256) {
        int s = src[e], d = dst[e];
        unsigned bd = ((unsigned)d) >> BSH;
        if (bd < (unsigned)NBUCK) {
            int r = atomicAdd(&curD[bd], 1);
            unsigned idx = (unsigned)(baseD[bd] + r);
            if (idx < (unsigned)NE) pairsD[idx] = make_uint2((unsigned)s, (unsigned)d);
        }
        unsigned bs = ((unsigned)s) >> BSH;
        if (bs < (unsigned)NBUCK) {
            int r = atomicAdd(&curS[bs], 1);
            unsigned idx = (unsigned)(baseS[bs] + r);
            if (idx < (unsigned)NE)
                packS[idx] = (((unsigned)s & 255u) << 24) | ((unsigned)d & 0xFFFFFFu);
        }
    }
}

// ---------------- pass B1: degree histogram + in-bucket scan -> offs + invd ----------------
__global__ __launch_bounds__(256) void k_pb1(const uint2* __restrict__ pairs, const int* __restrict__ bucketStart,
                                             int* __restrict__ offs, float* __restrict__ invd)
{
    __shared__ int dcnt[256];
    __shared__ int sscan[256];
    int t = threadIdx.x;
    dcnt[t] = 0;
    __syncthreads();
    int b = blockIdx.x;
    int base = b << BSH;
    int p0 = bucketStart[b], p1 = bucketStart[b + 1];
    for (int i = p0 + t; i < p1; i += 256) {
        unsigned li = pairs[i].y - (unsigned)base;
        if (li < 256u) atomicAdd(&dcnt[li], 1);
    }
    __syncthreads();
    int my = dcnt[t];
    sscan[t] = my;
    __syncthreads();
    for (int o = 1; o < 256; o <<= 1) {
        int v = (t >= o) ? sscan[t - o] : 0;
        __syncthreads();
        sscan[t] += v;
        __syncthreads();
    }
    if (base + t < NN) {
        offs[base + t] = p0 + (sscan[t] - my);
        invd[base + t] = 1.0f / (float)max(my, 1);
    }
    if (b == NBUCK - 1 && t == 0) offs[NN] = NE;
}

// ---------------- wsrc via src-buckets: LDS accumulate, coalesced write, zero global atomics ----------------
__global__ __launch_bounds__(256) void k_wsrc2(const unsigned* __restrict__ packS, const int* __restrict__ bucketStartS,
                                               const float* __restrict__ invd, float* __restrict__ wsrc)
{
    __shared__ float wacc[256];
    int t = threadIdx.x;
    wacc[t] = 0.f;
    __syncthreads();
    int b = blockIdx.x;
    int base = b << BSH;
    int p0 = bucketStartS[b], p1 = bucketStartS[b + 1];
    for (int i = p0 + t; i < p1; i += 256) {
        unsigned v = packS[i];
        unsigned li = v >> 24;
        unsigned dy = v & 0xFFFFFFu;
        if (dy >= (unsigned)NN) dy = 0u;
        atomicAdd(&wacc[li], invd[dy]);
    }
    __syncthreads();
    if (base + t < NN) wsrc[base + t] = wacc[t];
}

// ---------------- pass B2: in-bucket sort via LDS cursors + staging ----------------
__global__ __launch_bounds__(256) void k_pb2(const uint2* __restrict__ pairs, const int* __restrict__ offs,
                                             int* __restrict__ esrc)
{
    __shared__ int loffs[257];
    __shared__ int cur[256];
    __shared__ int S[CAP];
    int t = threadIdx.x;
    int b = blockIdx.x;
    int base = b << BSH;
    int nEnd = min(base + 256, NN);
    int nn = nEnd - base;
    int o0 = offs[base];
    for (int i = t; i <= nn; i += 256) loffs[i] = offs[base + i] - o0;   // covers loffs[nn] always
    cur[t] = 0;
    for (int i = t; i < CAP; i += 256) S[i] = 0;
    __syncthreads();
    int cnt = loffs[nn];
    if (cnt <= CAP) {
        for (int i = t; i < cnt; i += 256) {
            uint2 pr = pairs[o0 + i];
            unsigned li = pr.y - (unsigned)base;
            if (li > 255u) li = 255u;
            int pos = loffs[li] + atomicAdd(&cur[li], 1);
            if ((unsigned)pos >= (unsigned)cnt) pos = cnt - 1;
            S[pos] = (int)pr.x;
        }
        __syncthreads();
        for (int i = t; i < cnt; i += 256) esrc[o0 + i] = S[i];
    } else {
        for (int i = t; i < cnt; i += 256) {
            uint2 pr = pairs[o0 + i];
            unsigned li = pr.y - (unsigned)base;
            if (li > 255u) li = 255u;
            int pos = loffs[li] + atomicAdd(&cur[li], 1);
            if ((unsigned)pos >= (unsigned)cnt) pos = cnt - 1;
            esrc[o0 + pos] = (int)pr.x;
        }
    }
}

// ---------------- mean aggregation from fp8 rows: 1 wave/node, 8 edge-slots x 8 lanes x 16B, packed-f32 math ----------------
__global__ __launch_bounds__(256) void k_aggregate(const unsigned char* __restrict__ inf8, bf16* __restrict__ out,
                                                   const int* __restrict__ offs, const int* __restrict__ esrc,
                                                   const float* __restrict__ invd,
                                                   const float* __restrict__ scsh, int use_ss)
{
    int row = blockIdx.x * 4 + (threadIdx.x >> 6);
    if (row >= NN) return;
    int lane = threadIdx.x & 63;
    int grp = lane >> 3;           // 8 slot groups
    int c0 = (lane & 7) * 16;      // 16 fp8 cols per lane
    f2 sc2[8], sh2[8];
    if (use_ss) {
#pragma unroll
        for (int j = 0; j < 8; j++) {
            sc2[j].x = scsh[c0 + 2*j];     sc2[j].y = scsh[c0 + 2*j + 1];
            sh2[j].x = scsh[128 + c0 + 2*j]; sh2[j].y = scsh[128 + c0 + 2*j + 1];
        }
    }
    int e0 = offs[row], e1 = offs[row + 1];
    f2 a[8];
#pragma unroll
    for (int j = 0; j < 8; j++) { a[j].x = 0.f; a[j].y = 0.f; }

    // unpack uint4 (16 fp8) -> 8 f2, accumulate (packed fma/max when use_ss)
    auto accum = [&](uint4 u) {
        unsigned w[4] = {u.x, u.y, u.z, u.w};
#pragma unroll
        for (int k = 0; k < 4; k++) {
            f2 lo = __builtin_amdgcn_cvt_pk_f32_fp8(w[k], 0);
            f2 hi = __builtin_amdgcn_cvt_pk_f32_fp8(w[k], 1);
            if (use_ss) {
                a[2*k]   += pkmax0(lo * sc2[2*k]   + sh2[2*k]);
                a[2*k+1] += pkmax0(hi * sc2[2*k+1] + sh2[2*k+1]);
            } else {
                a[2*k]   += lo;
                a[2*k+1] += hi;
            }
        }
    };

    int e = e0 + grp;
    for (; e + 8 < e1; e += 16) {
        int s0 = esrc[e], s1 = esrc[e + 8];
        uint4 u0 = *(const uint4*)&inf8[(size_t)s0 * 128 + c0];
        uint4 u1 = *(const uint4*)&inf8[(size_t)s1 * 128 + c0];
        accum(u0);
        accum(u1);
    }
    if (e < e1) {
        int s0 = esrc[e];
        uint4 u0 = *(const uint4*)&inf8[(size_t)s0 * 128 + c0];
        accum(u0);
    }
    // reduce across the 8 slot groups
#pragma unroll
    for (int j = 0; j < 8; j++) {
        a[j].x += __shfl_xor(a[j].x, 8);  a[j].y += __shfl_xor(a[j].y, 8);
        a[j].x += __shfl_xor(a[j].x, 16); a[j].y += __shfl_xor(a[j].y, 16);
        a[j].x += __shfl_xor(a[j].x, 32); a[j].y += __shfl_xor(a[j].y, 32);
    }
    if (grp == 0) {
        float id = invd[row];
        bf16x8 o0, o1;
#pragma unroll
        for (int j = 0; j < 4; j++) {
            o0.v[2*j]   = f2b(a[j].x * id);
            o0.v[2*j+1] = f2b(a[j].y * id);
            o1.v[2*j]   = f2b(a[j+4].x * id);
            o1.v[2*j+1] = f2b(a[j+4].y * id);
        }
        *(bf16x8*)&out[(size_t)row * 128 + c0] = o0;
        *(bf16x8*)&out[(size_t)row * 128 + c0 + 8] = o1;
    }
}

// ---------------- MFMA dual GEMM: out = relu(T(Hs)@Ws + Ag@Wn + b); fused BN stats; optional fp8 copy ----------------
#define GM 128
__global__ __launch_bounds__(256) void k_gemm_mfma(const bf16* __restrict__ Hs, const bf16* __restrict__ Ag,
                                                   const bf16* __restrict__ Wst, const bf16* __restrict__ Wnt,
                                                   const float* __restrict__ bias,
                                                   const float* __restrict__ scsh, int use_ss,
                                                   bf16* __restrict__ outp, unsigned char* __restrict__ outf8,
                                                   float* __restrict__ bnsums)
{
    __shared__ bf16 smem[2][128][72];
    __shared__ float sredsum[128], sredsq[128];
    int t = threadIdx.x;
    int row0 = blockIdx.x * GM;
    int lane = t & 63;
    int l16 = lane & 15;
    int quad = lane >> 4;
    int m0w = (t >> 6) * 32;

    if (t < 128) { sredsum[t] = 0.f; sredsq[t] = 0.f; }

    f4 acc[2][8];
#pragma unroll
    for (int rt = 0; rt < 2; rt++)
#pragma unroll
        for (int ct = 0; ct < 8; ct++) { f4 z = {0.f, 0.f, 0.f, 0.f}; acc[rt][ct] = z; }

    for (int kc = 0; kc < 128; kc += 64) {
#pragma unroll
        for (int i = 0; i < 4; i++) {
            int f = i * 256 + t;
            int row = f >> 3;
            int col8 = (f & 7) * 8;
            int grow = row0 + row;
            bf16x8 hv, av;
            if (grow < NN) {
                hv = *(const bf16x8*)&Hs[(size_t)grow * 128 + kc + col8];
                av = *(const bf16x8*)&Ag[(size_t)grow * 128 + kc + col8];
            } else {
#pragma unroll
                for (int j = 0; j < 8; j++) { hv.v[j] = f2b(0.f); av.v[j] = f2b(0.f); }
            }
            if (use_ss) {
#pragma unroll
                for (int j = 0; j < 8; j++) {
                    int k = kc + col8 + j;
                    hv.v[j] = f2b(fmaxf(b2f(hv.v[j]) * scsh[k] + scsh[128 + k], 0.f));
                }
            }
            *(bf16x8*)&smem[0][row][col8] = hv;
            *(bf16x8*)&smem[1][row][col8] = av;
        }
        __syncthreads();
#pragma unroll
        for (int ks2 = 0; ks2 < 2; ks2++) {
            int ko = ks2 * 32 + quad * 8;
            bfrag ah0 = *(const bfrag*)&smem[0][m0w + l16][ko];
            bfrag ah1 = *(const bfrag*)&smem[0][m0w + 16 + l16][ko];
            bfrag aa0 = *(const bfrag*)&smem[1][m0w + l16][ko];
            bfrag aa1 = *(const bfrag*)&smem[1][m0w + 16 + l16][ko];
            int kg = kc + ks2 * 32 + quad * 8;
#pragma unroll
            for (int ct = 0; ct < 8; ct++) {
                bfrag bs  = *(const bfrag*)&Wst[(ct * 16 + l16) * 128 + kg];
                bfrag bnf = *(const bfrag*)&Wnt[(ct * 16 + l16) * 128 + kg];
                acc[0][ct] = __builtin_amdgcn_mfma_f32_16x16x32_bf16(ah0, bs,  acc[0][ct], 0, 0, 0);
                acc[0][ct] = __builtin_amdgcn_mfma_f32_16x16x32_bf16(aa0, bnf, acc[0][ct], 0, 0, 0);
                acc[1][ct] = __builtin_amdgcn_mfma_f32_16x16x32_bf16(ah1, bs,  acc[1][ct], 0, 0, 0);
                acc[1][ct] = __builtin_amdgcn_mfma_f32_16x16x32_bf16(aa1, bnf, acc[1][ct], 0, 0, 0);
            }
        }
        __syncthreads();
    }

    bf16 (*sout)[136] = (bf16(*)[136])&smem[0][0][0];
    float psum[8], psq[8];
#pragma unroll
    for (int ct = 0; ct < 8; ct++) {
        float bv = bias[ct * 16 + l16];
        float s = 0.f, s2 = 0.f;
#pragma unroll
        for (int rt = 0; rt < 2; rt++) {
#pragma unroll
            for (int r = 0; r < 4; r++) {
                int lrow = m0w + rt * 16 + quad * 4 + r;
                float v = fmaxf(acc[rt][ct][r] + bv, 0.f);
                sout[lrow][ct * 16 + l16] = f2b(v);
                if (row0 + lrow < NN) { s += v; s2 += v * v; }
            }
        }
        psum[ct] = s; psq[ct] = s2;
    }
#pragma unroll
    for (int ct = 0; ct < 8; ct++) {
        psum[ct] += __shfl_xor(psum[ct], 16); psum[ct] += __shfl_xor(psum[ct], 32);
        psq[ct]  += __shfl_xor(psq[ct], 16);  psq[ct]  += __shfl_xor(psq[ct], 32);
    }
    if (lane < 16) {
#pragma unroll
        for (int ct = 0; ct < 8; ct++) {
            atomicAdd(&sredsum[ct * 16 + lane], psum[ct]);
            atomicAdd(&sredsq[ct * 16 + lane],  psq[ct]);
        }
    }
    __syncthreads();
#pragma unroll
    for (int i = 0; i < 8; i++) {
        int f = i * 256 + t;
        int row = f >> 4;
        int c16 = f & 15;
        int grow = row0 + row;
        if (grow < NN) {
            bf16x8 ov = *(const bf16x8*)&sout[row][c16 * 8];
            *(bf16x8*)&outp[(size_t)grow * 128 + c16 * 8] = ov;
            if (outf8) {
                *(uint2*)&outf8[(size_t)grow * 128 + c16 * 8] =
                    pk8_fp8(b2f(ov.v[0]), b2f(ov.v[1]), b2f(ov.v[2]), b2f(ov.v[3]),
                            b2f(ov.v[4]), b2f(ov.v[5]), b2f(ov.v[6]), b2f(ov.v[7]));
            }
        }
    }
    if (t < 128) {
        atomicAdd(&bnsums[t], sredsum[t]);
        atomicAdd(&bnsums[128 + t], sredsq[t]);
    }
}

__global__ void k_bn_fin(const float* __restrict__ sums, const float* __restrict__ g,
                         const float* __restrict__ be, float* __restrict__ scsh)
{
    int t = threadIdx.x;
    if (t < 128) {
        float mu = sums[t] / (float)NN;
        float var = sums[128 + t] / (float)NN - mu * mu;
        float sc = g[t] * rsqrtf(var + BN_EPS);
        scsh[t] = sc;
        scsh[128 + t] = be[t] - mu * sc;
    }
}

// ---------------- layer-2 reduction (vectorized) ----------------
__global__ __launch_bounds__(256) void k_l2_reduce(const bf16* __restrict__ h, const float* __restrict__ scsh,
                                                   const float* __restrict__ wsrc, float* __restrict__ ue)
{
    __shared__ float su[128], se[128];
    int t = threadIdx.x;
    if (t < 128) { su[t] = 0.f; se[t] = 0.f; }
    __syncthreads();
    int c0 = (t & 15) * 8;
    int rof = t >> 4;
    float sc[8], sh[8];
#pragma unroll
    for (int j = 0; j < 8; j++) { sc[j] = scsh[c0 + j]; sh[j] = scsh[128 + c0 + j]; }
    float u[8], es[8];
#pragma unroll
    for (int j = 0; j < 8; j++) { u[j] = 0.f; es[j] = 0.f; }
    int rpb = (NN + gridDim.x - 1) / gridDim.x;
    int r0 = blockIdx.x * rpb;
    int r1 = min(r0 + rpb, NN);
    for (int r = r0 + rof; r < r1; r += 16) {
        bf16x8 v = *(const bf16x8*)&h[(size_t)r * 128 + c0];
        float w = wsrc[r];
#pragma unroll
        for (int j = 0; j < 8; j++) {
            float x = fmaxf(b2f(v.v[j]) * sc[j] + sh[j], 0.f);
            u[j] += x; es[j] += w * x;
        }
    }
#pragma unroll
    for (int j = 0; j < 8; j++) { atomicAdd(&su[c0 + j], u[j]); atomicAdd(&se[c0 + j], es[j]); }
    __syncthreads();
    if (t < 128) { atomicAdd(&ue[t], su[t]); atomicAdd(&ue[128 + t], se[t]); }
}

__global__ void k_final(const float* __restrict__ ue, const float* __restrict__ Ws2,
                        const float* __restrict__ Wn2, const float* __restrict__ b2,
                        float* __restrict__ out)
{
    __shared__ float logit[32];
    int t = threadIdx.x;
    const float inv = 1.0f / (float)NN;
    if (t < 32) {
        float acc = b2[t];
        for (int k = 0; k < 128; k++)
            acc += (ue[k] * inv) * Ws2[k * 32 + t] + (ue[128 + k] * inv) * Wn2[k * 32 + t];
        logit[t] = acc;
    }
    __syncthreads();
    if (t < 32) {
        float m = -1e30f;
        for (int j = 0; j < 32; j++) m = fmaxf(m, logit[j]);
        float s = 0.f;
        for (int j = 0; j < 32; j++) s += expf(logit[j] - m);
        out[t] = expf(logit[t] - m) / s;
    }
}

extern "C" void kernel_launch(void* const* d_in, const int* in_sizes, int n_in,
                              void* d_out, int out_size, void* d_ws, size_t ws_size,
                              hipStream_t stream)
{
    const float* feat = (const float*)d_in[0];
    const int*   src  = (const int*)d_in[1];
    const int*   dst  = (const int*)d_in[2];
    const float* Ws0  = (const float*)d_in[3];
    const float* Wn0  = (const float*)d_in[4];
    const float* b0   = (const float*)d_in[5];
    const float* Ws1  = (const float*)d_in[6];
    const float* Wn1  = (const float*)d_in[7];
    const float* b1   = (const float*)d_in[8];
    const float* Ws2  = (const float*)d_in[9];
    const float* Wn2  = (const float*)d_in[10];
    const float* b2   = (const float*)d_in[11];
    const float* g0   = (const float*)d_in[12];
    const float* be0  = (const float*)d_in[13];
    const float* g1   = (const float*)d_in[14];
    const float* be1  = (const float*)d_in[15];

    char* p = (char*)d_ws;
    auto alloc = [&](size_t b) -> void* {
        void* r = (void*)p;
        p += (b + 255) & ~(size_t)255;
        return r;
    };
    bf16* BB     = (bf16*)alloc((size_t)NN * 128 * 2);   // featbf -> h0 (in-place)
    bf16* A      = (bf16*)alloc((size_t)NN * 128 * 2);   // pairsD alias -> agg0 -> agg1 -> h1
    unsigned char* F8 = (unsigned char*)alloc((size_t)NN * 128); // fp8 feat -> fp8 h0
    unsigned* packS = (unsigned*)alloc((size_t)NE * 4);  // src-sorted packed; esrc aliases it
    int*  offs   = (int*)alloc((size_t)(NN + 1) * 4);
    float* invd  = (float*)alloc((size_t)NN * 4);
    float* wsrc  = (float*)alloc((size_t)NN * 4);
    float* bn0   = (float*)alloc(256 * 4);
    float* scsh0 = (float*)alloc(256 * 4);
    float* bn1   = (float*)alloc(256 * 4);
    float* scsh1 = (float*)alloc(256 * 4);
    float* ue    = (float*)alloc(256 * 4);
    bf16* Ws0t   = (bf16*)alloc(16384 * 2);
    bf16* Wn0t   = (bf16*)alloc(16384 * 2);
    bf16* Ws1t   = (bf16*)alloc(16384 * 2);
    bf16* Wn1t   = (bf16*)alloc(16384 * 2);
    int*  bucketCountD = (int*)alloc((NBUCK + 1) * 4);
    int*  bucketStartD = (int*)alloc((NBUCK + 1) * 4);
    int*  blockBaseD   = (int*)alloc((size_t)ABLK * NBUCK * 4);
    int*  bucketCountS = (int*)alloc((NBUCK + 1) * 4);
    int*  bucketStartS = (int*)alloc((NBUCK + 1) * 4);
    int*  blockBaseS   = (int*)alloc((size_t)ABLK * NBUCK * 4);

    // pairsD aliases A (12.8MB <= 25.6MB): A dead until first k_aggregate (after k_pb2).
    uint2* pairsD = (uint2*)A;
    // esrc aliases packS (both NE*4): packS dead after k_wsrc2; k_pb2 writes esrc after.
    int* esrc = (int*)packS;

    hipMemsetAsync(bucketCountD, 0, (NBUCK + 1) * 4, stream);
    hipMemsetAsync(bucketCountS, 0, (NBUCK + 1) * 4, stream);
    hipMemsetAsync(bn0, 0, 256 * 4, stream);
    hipMemsetAsync(bn1, 0, 256 * 4, stream);
    hipMemsetAsync(ue, 0, 256 * 4, stream);

    const int GB = (NN + GM - 1) / GM;

    k_convert<<<(NN * 128) / (256 * 8), 256, 0, stream>>>(feat, BB, F8, NN * 128);
    k_wtrans<<<256, 256, 0, stream>>>(Ws0, Wn0, Ws1, Wn1, Ws0t, Wn0t, Ws1t, Wn1t);

    // ---- CSR build: dual bucketed counting sort (dst for esrc/offs, src for wsrc) ----
    k_pa1<<<ABLK, 256, 0, stream>>>(dst, src, bucketCountD, blockBaseD, bucketCountS, blockBaseS);
    k_bscan2<<<2, 512, 0, stream>>>(bucketCountD, bucketStartD, bucketCountS, bucketStartS);
    k_pa2<<<ABLK, 256, 0, stream>>>(src, dst, bucketStartD, blockBaseD, bucketStartS, blockBaseS, pairsD, packS);
    k_pb1<<<NBUCK, 256, 0, stream>>>(pairsD, bucketStartD, offs, invd);
    k_wsrc2<<<NBUCK, 256, 0, stream>>>(packS, bucketStartS, invd, wsrc);    // last read of packS
    k_pb2<<<NBUCK, 256, 0, stream>>>(pairsD, offs, esrc);                   // esrc overwrites packS region

    // ---- layer 0 ----
    k_aggregate<<<(NN + 3) / 4, 256, 0, stream>>>(F8, A, offs, esrc, invd, nullptr, 0);
    k_gemm_mfma<<<GB, 256, 0, stream>>>(BB, A, Ws0t, Wn0t, b0, nullptr, 0, BB, F8, bn0);  // F8 := fp8(h0)
    k_bn_fin<<<1, 128, 0, stream>>>(bn0, g0, be0, scsh0);

    // ---- layer 1 ----
    k_aggregate<<<(NN + 3) / 4, 256, 0, stream>>>(F8, A, offs, esrc, invd, scsh0, 1);
    k_gemm_mfma<<<GB, 256, 0, stream>>>(BB, A, Ws1t, Wn1t, b1, scsh0, 1, A, nullptr, bn1);
    k_bn_fin<<<1, 128, 0, stream>>>(bn1, g1, be1, scsh1);

    // ---- layer 2 (collapsed to column reductions) ----
    k_l2_reduce<<<256, 256, 0, stream>>>(A, scsh1, wsrc, ue);
    k_final<<<1, 64, 0, stream>>>(ue, Ws2, Wn2, b2, (float*)d_out);
}

// Round 11
// 498.675 us; speedup vs baseline: 1.0901x; 1.0901x over previous
//
#include <hip/hip_runtime.h>
#include <hip/hip_bf16.h>

typedef __hip_bfloat16 bf16;
typedef __hip_bfloat162 bf162;

#define NN 100000
#define NE 1600000
#define BN_EPS 1e-5f

// bucketed CSR build
#define BSH 8
#define NBUCK ((NN + 255) >> BSH)      // 391
#define ABLK 128
#define EPBA ((NE + ABLK - 1) / ABLK)  // 12500
#define CAP 6144                       // staging capacity (mean bucket = 4096, sigma ~ 64)

struct alignas(16) bf16x8 { bf16 v[8]; };

typedef __bf16 bfrag __attribute__((ext_vector_type(8)));
typedef float f4 __attribute__((ext_vector_type(4)));
typedef float f2 __attribute__((ext_vector_type(2)));

static __device__ __forceinline__ float b2f(bf16 x){ return __bfloat162float(x); }
static __device__ __forceinline__ bf16 f2b(float x){ return __float2bfloat16(x); }

// pack 8 fp32 -> 8 fp8(e4m3, hw OCP on gfx950) as uint2
static __device__ __forceinline__ uint2 pk8_fp8(float x0,float x1,float x2,float x3,
                                                float x4,float x5,float x6,float x7)
{
    int lo = __builtin_amdgcn_cvt_pk_fp8_f32(x0, x1, 0, 0);
    lo = __builtin_amdgcn_cvt_pk_fp8_f32(x2, x3, lo, 1);
    int hi = __builtin_amdgcn_cvt_pk_fp8_f32(x4, x5, 0, 0);
    hi = __builtin_amdgcn_cvt_pk_fp8_f32(x6, x7, hi, 1);
    return make_uint2((unsigned)lo, (unsigned)hi);
}

// ---------------- fp32 -> bf16 + fp8 convert ----------------
__global__ __launch_bounds__(256) void k_convert(const float* __restrict__ in, bf16* __restrict__ out,
                                                 unsigned char* __restrict__ outf8, int n)
{
    int i = (blockIdx.x * 256 + threadIdx.x) * 8;
    if (i + 7 < n) {
        float4 a = *(const float4*)(in + i);
        float4 b = *(const float4*)(in + i + 4);
        bf16x8 o;
        o.v[0]=f2b(a.x); o.v[1]=f2b(a.y); o.v[2]=f2b(a.z); o.v[3]=f2b(a.w);
        o.v[4]=f2b(b.x); o.v[5]=f2b(b.y); o.v[6]=f2b(b.z); o.v[7]=f2b(b.w);
        *(bf16x8*)(out + i) = o;
        *(uint2*)(outf8 + i) = pk8_fp8(a.x,a.y,a.z,a.w,b.x,b.y,b.z,b.w);
    }
}

// ---------------- weight transpose+convert: Wt[n][k] = bf16(W[k][n]) ----------------
__global__ __launch_bounds__(256) void k_wtrans(const float* __restrict__ W0, const float* __restrict__ W1,
                                                const float* __restrict__ W2, const float* __restrict__ W3,
                                                bf16* __restrict__ T0, bf16* __restrict__ T1,
                                                bf16* __restrict__ T2, bf16* __restrict__ T3)
{
    int m = blockIdx.x >> 6;
    int t = (blockIdx.x & 63) * 256 + threadIdx.x;
    const float* W = (m == 0) ? W0 : (m == 1) ? W1 : (m == 2) ? W2 : W3;
    bf16* T = (m == 0) ? T0 : (m == 1) ? T1 : (m == 2) ? T2 : T3;
    int n = t >> 7, k = t & 127;
    T[n * 128 + k] = f2b(W[k * 128 + n]);
}

// ---------------- pass A1: per-block bucket histograms for BOTH dst and src ----------------
__global__ __launch_bounds__(256) void k_pa1(const int* __restrict__ dst, const int* __restrict__ src,
                                             int* __restrict__ bucketCountD, int* __restrict__ blockBaseD,
                                             int* __restrict__ bucketCountS, int* __restrict__ blockBaseS)
{
    __shared__ int histD[NBUCK];
    __shared__ int histS[NBUCK];
    int t = threadIdx.x;
    for (int i = t; i < NBUCK; i += 256) { histD[i] = 0; histS[i] = 0; }
    __syncthreads();
    int e0 = blockIdx.x * EPBA, e1 = min(e0 + EPBA, NE);
    for (int e = e0 + t; e < e1; e += 256) {
        unsigned bd = ((unsigned)dst[e]) >> BSH;
        unsigned bs = ((unsigned)src[e]) >> BSH;
        if (bd < (unsigned)NBUCK) atomicAdd(&histD[bd], 1);
        if (bs < (unsigned)NBUCK) atomicAdd(&histS[bs], 1);
    }
    __syncthreads();
    for (int i = t; i < NBUCK; i += 256) {
        blockBaseD[blockIdx.x * NBUCK + i] = atomicAdd(&bucketCountD[i], histD[i]);
        blockBaseS[blockIdx.x * NBUCK + i] = atomicAdd(&bucketCountS[i], histS[i]);
    }
}

// ---------------- bucket scan x2 (391 -> exclusive), block 0 = D, block 1 = S ----------------
__global__ __launch_bounds__(512) void k_bscan2(const int* __restrict__ cntD, int* __restrict__ startD,
                                                const int* __restrict__ cntS, int* __restrict__ startS)
{
    __shared__ int sd[512];
    const int* cnt = (blockIdx.x == 0) ? cntD : cntS;
    int* start = (blockIdx.x == 0) ? startD : startS;
    int t = threadIdx.x;
    int v = (t < NBUCK) ? cnt[t] : 0;
    sd[t] = v;
    __syncthreads();
    for (int o = 1; o < 512; o <<= 1) {
        int x = (t >= o) ? sd[t - o] : 0;
        __syncthreads();
        sd[t] += x;
        __syncthreads();
    }
    if (t < NBUCK) start[t] = sd[t] - v;
    if (t == 0) start[NBUCK] = NE;
}

// ---------------- pass A2: scatter pairsD (by dst) + packed packS (by src: (src&255)<<24 | dst) ----------------
__global__ __launch_bounds__(256) void k_pa2(const int* __restrict__ src, const int* __restrict__ dst,
                                             const int* __restrict__ bucketStartD, const int* __restrict__ blockBaseD,
                                             const int* __restrict__ bucketStartS, const int* __restrict__ blockBaseS,
                                             uint2* __restrict__ pairsD, unsigned* __restrict__ packS)
{
    __shared__ int baseD[NBUCK];
    __shared__ int curD[NBUCK];
    __shared__ int baseS[NBUCK];
    __shared__ int curS[NBUCK];
    int t = threadIdx.x;
    for (int i = t; i < NBUCK; i += 256) {
        baseD[i] = bucketStartD[i] + blockBaseD[blockIdx.x * NBUCK + i];
        curD[i] = 0;
        baseS[i] = bucketStartS[i] + blockBaseS[blockIdx.x * NBUCK + i];
        curS[i] = 0;
    }
    __syncthreads();
    int e0 = blockIdx.x * EPBA, e1 = min(e0 + EPBA, NE);
    for (int e = e0 + t; e < e1; e += 256) {
        int s = src[e], d = dst[e];
        unsigned bd = ((unsigned)d) >> BSH;
        if (bd < (unsigned)NBUCK) {
            int r = atomicAdd(&curD[bd], 1);
            unsigned idx = (unsigned)(baseD[bd] + r);
            if (idx < (unsigned)NE) pairsD[idx] = make_uint2((unsigned)s, (unsigned)d);
        }
        unsigned bs = ((unsigned)s) >> BSH;
        if (bs < (unsigned)NBUCK) {
            int r = atomicAdd(&curS[bs], 1);
            unsigned idx = (unsigned)(baseS[bs] + r);
            if (idx < (unsigned)NE)
                packS[idx] = (((unsigned)s & 255u) << 24) | ((unsigned)d & 0xFFFFFFu);
        }
    }
}

// ---------------- pass B1: degree histogram + in-bucket scan -> offs + invd ----------------
__global__ __launch_bounds__(256) void k_pb1(const uint2* __restrict__ pairs, const int* __restrict__ bucketStart,
                                             int* __restrict__ offs, float* __restrict__ invd)
{
    __shared__ int dcnt[256];
    __shared__ int sscan[256];
    int t = threadIdx.x;
    dcnt[t] = 0;
    __syncthreads();
    int b = blockIdx.x;
    int base = b << BSH;
    int p0 = bucketStart[b], p1 = bucketStart[b + 1];
    for (int i = p0 + t; i < p1; i += 256) {
        unsigned li = pairs[i].y - (unsigned)base;
        if (li < 256u) atomicAdd(&dcnt[li], 1);
    }
    __syncthreads();
    int my = dcnt[t];
    sscan[t] = my;
    __syncthreads();
    for (int o = 1; o < 256; o <<= 1) {
        int v = (t >= o) ? sscan[t - o] : 0;
        __syncthreads();
        sscan[t] += v;
        __syncthreads();
    }
    if (base + t < NN) {
        offs[base + t] = p0 + (sscan[t] - my);
        invd[base + t] = 1.0f / (float)max(my, 1);
    }
    if (b == NBUCK - 1 && t == 0) offs[NN] = NE;
}

// ---------------- wsrc via src-buckets: LDS accumulate, coalesced write, zero global atomics ----------------
__global__ __launch_bounds__(256) void k_wsrc2(const unsigned* __restrict__ packS, const int* __restrict__ bucketStartS,
                                               const float* __restrict__ invd, float* __restrict__ wsrc)
{
    __shared__ float wacc[256];
    int t = threadIdx.x;
    wacc[t] = 0.f;
    __syncthreads();
    int b = blockIdx.x;
    int base = b << BSH;
    int p0 = bucketStartS[b], p1 = bucketStartS[b + 1];
    for (int i = p0 + t; i < p1; i += 256) {
        unsigned v = packS[i];
        unsigned li = v >> 24;
        unsigned dy = v & 0xFFFFFFu;
        if (dy >= (unsigned)NN) dy = 0u;
        atomicAdd(&wacc[li], invd[dy]);
    }
    __syncthreads();
    if (base + t < NN) wsrc[base + t] = wacc[t];
}

// ---------------- pass B2: in-bucket sort via LDS cursors + staging ----------------
__global__ __launch_bounds__(256) void k_pb2(const uint2* __restrict__ pairs, const int* __restrict__ offs,
                                             int* __restrict__ esrc)
{
    __shared__ int loffs[257];
    __shared__ int cur[256];
    __shared__ int S[CAP];
    int t = threadIdx.x;
    int b = blockIdx.x;
    int base = b << BSH;
    int nEnd = min(base + 256, NN);
    int nn = nEnd - base;
    int o0 = offs[base];
    for (int i = t; i <= nn; i += 256) loffs[i] = offs[base + i] - o0;   // covers loffs[nn] always
    cur[t] = 0;
    for (int i = t; i < CAP; i += 256) S[i] = 0;
    __syncthreads();
    int cnt = loffs[nn];
    if (cnt <= CAP) {
        for (int i = t; i < cnt; i += 256) {
            uint2 pr = pairs[o0 + i];
            unsigned li = pr.y - (unsigned)base;
            if (li > 255u) li = 255u;
            int pos = loffs[li] + atomicAdd(&cur[li], 1);
            if ((unsigned)pos >= (unsigned)cnt) pos = cnt - 1;
            S[pos] = (int)pr.x;
        }
        __syncthreads();
        for (int i = t; i < cnt; i += 256) esrc[o0 + i] = S[i];
    } else {
        for (int i = t; i < cnt; i += 256) {
            uint2 pr = pairs[o0 + i];
            unsigned li = pr.y - (unsigned)base;
            if (li > 255u) li = 255u;
            int pos = loffs[li] + atomicAdd(&cur[li], 1);
            if ((unsigned)pos >= (unsigned)cnt) pos = cnt - 1;
            esrc[o0 + pos] = (int)pr.x;
        }
    }
}

// ---------------- mean aggregation from fp8 rows: 1 wave/node, 4 edge-slots x 16 lanes x 8B ----------------
// Round-9 structure (4 independent gathers in flight) + masked-chunk tail (no serial tail loads).
__global__ __launch_bounds__(256) void k_aggregate(const unsigned char* __restrict__ inf8, bf16* __restrict__ out,
                                                   const int* __restrict__ offs, const int* __restrict__ esrc,
                                                   const float* __restrict__ invd,
                                                   const float* __restrict__ scsh, int use_ss)
{
    int row = blockIdx.x * 4 + (threadIdx.x >> 6);
    if (row >= NN) return;
    int lane = threadIdx.x & 63;
    int grp = lane >> 4;
    int c0 = (lane & 15) * 8;
    float sc[8], sh[8];
    if (use_ss) {
#pragma unroll
        for (int j = 0; j < 8; j++) { sc[j] = scsh[c0 + j]; sh[j] = scsh[128 + c0 + j]; }
    }
    int e0 = offs[row], e1 = offs[row + 1];
    float a[8];
#pragma unroll
    for (int j = 0; j < 8; j++) a[j] = 0.f;

    auto unpack = [&](uint2 u, float* v) {
        f2 p0 = __builtin_amdgcn_cvt_pk_f32_fp8(u.x, 0);
        f2 p1 = __builtin_amdgcn_cvt_pk_f32_fp8(u.x, 1);
        f2 p2 = __builtin_amdgcn_cvt_pk_f32_fp8(u.y, 0);
        f2 p3 = __builtin_amdgcn_cvt_pk_f32_fp8(u.y, 1);
        v[0]=p0.x; v[1]=p0.y; v[2]=p1.x; v[3]=p1.y; v[4]=p2.x; v[5]=p2.y; v[6]=p3.x; v[7]=p3.y;
    };

    int e = e0 + grp;
    for (; e + 12 < e1; e += 16) {
        int s0 = esrc[e], s1 = esrc[e + 4], s2 = esrc[e + 8], s3 = esrc[e + 12];
        uint2 u0 = *(const uint2*)&inf8[(size_t)s0 * 128 + c0];
        uint2 u1 = *(const uint2*)&inf8[(size_t)s1 * 128 + c0];
        uint2 u2 = *(const uint2*)&inf8[(size_t)s2 * 128 + c0];
        uint2 u3 = *(const uint2*)&inf8[(size_t)s3 * 128 + c0];
        float v0[8], v1[8], v2[8], v3[8];
        unpack(u0, v0); unpack(u1, v1); unpack(u2, v2); unpack(u3, v3);
        if (use_ss) {
#pragma unroll
            for (int j = 0; j < 8; j++)
                a[j] += fmaxf(v0[j] * sc[j] + sh[j], 0.f) + fmaxf(v1[j] * sc[j] + sh[j], 0.f)
                      + fmaxf(v2[j] * sc[j] + sh[j], 0.f) + fmaxf(v3[j] * sc[j] + sh[j], 0.f);
        } else {
#pragma unroll
            for (int j = 0; j < 8; j++)
                a[j] += (v0[j] + v1[j]) + (v2[j] + v3[j]);
        }
    }
    // masked tail chunk: at most 3 remaining edges for this group (e, e+4, e+8) — issue together
    if (e < e1) {
        int i1 = e + 4, i2 = e + 8;
        float m1 = (i1 < e1) ? 1.f : 0.f;
        float m2 = (i2 < e1) ? 1.f : 0.f;
        if (i1 >= e1) i1 = e;
        if (i2 >= e1) i2 = e;
        int s0 = esrc[e], s1 = esrc[i1], s2 = esrc[i2];
        uint2 u0 = *(const uint2*)&inf8[(size_t)s0 * 128 + c0];
        uint2 u1 = *(const uint2*)&inf8[(size_t)s1 * 128 + c0];
        uint2 u2 = *(const uint2*)&inf8[(size_t)s2 * 128 + c0];
        float v0[8], v1[8], v2[8];
        unpack(u0, v0); unpack(u1, v1); unpack(u2, v2);
        if (use_ss) {
#pragma unroll
            for (int j = 0; j < 8; j++)
                a[j] += fmaxf(v0[j] * sc[j] + sh[j], 0.f)
                      + m1 * fmaxf(v1[j] * sc[j] + sh[j], 0.f)
                      + m2 * fmaxf(v2[j] * sc[j] + sh[j], 0.f);
        } else {
#pragma unroll
            for (int j = 0; j < 8; j++)
                a[j] += v0[j] + m1 * v1[j] + m2 * v2[j];
        }
    }
#pragma unroll
    for (int j = 0; j < 8; j++) {
        a[j] += __shfl_xor(a[j], 16);
        a[j] += __shfl_xor(a[j], 32);
    }
    if (grp == 0) {
        float id = invd[row];
        bf16x8 o;
#pragma unroll
        for (int j = 0; j < 8; j++) o.v[j] = f2b(a[j] * id);
        *(bf16x8*)&out[(size_t)row * 128 + c0] = o;
    }
}

// ---------------- MFMA dual GEMM: out = relu(T(Hs)@Ws + Ag@Wn + b); fused BN stats; optional fp8 copy ----------------
#define GM 128
__global__ __launch_bounds__(256) void k_gemm_mfma(const bf16* __restrict__ Hs, const bf16* __restrict__ Ag,
                                                   const bf16* __restrict__ Wst, const bf16* __restrict__ Wnt,
                                                   const float* __restrict__ bias,
                                                   const float* __restrict__ scsh, int use_ss,
                                                   bf16* __restrict__ outp, unsigned char* __restrict__ outf8,
                                                   float* __restrict__ bnsums)
{
    __shared__ bf16 smem[2][128][72];
    __shared__ float sredsum[128], sredsq[128];
    int t = threadIdx.x;
    int row0 = blockIdx.x * GM;
    int lane = t & 63;
    int l16 = lane & 15;
    int quad = lane >> 4;
    int m0w = (t >> 6) * 32;

    if (t < 128) { sredsum[t] = 0.f; sredsq[t] = 0.f; }

    f4 acc[2][8];
#pragma unroll
    for (int rt = 0; rt < 2; rt++)
#pragma unroll
        for (int ct = 0; ct < 8; ct++) { f4 z = {0.f, 0.f, 0.f, 0.f}; acc[rt][ct] = z; }

    for (int kc = 0; kc < 128; kc += 64) {
#pragma unroll
        for (int i = 0; i < 4; i++) {
            int f = i * 256 + t;
            int row = f >> 3;
            int col8 = (f & 7) * 8;
            int grow = row0 + row;
            bf16x8 hv, av;
            if (grow < NN) {
                hv = *(const bf16x8*)&Hs[(size_t)grow * 128 + kc + col8];
                av = *(const bf16x8*)&Ag[(size_t)grow * 128 + kc + col8];
            } else {
#pragma unroll
                for (int j = 0; j < 8; j++) { hv.v[j] = f2b(0.f); av.v[j] = f2b(0.f); }
            }
            if (use_ss) {
#pragma unroll
                for (int j = 0; j < 8; j++) {
                    int k = kc + col8 + j;
                    hv.v[j] = f2b(fmaxf(b2f(hv.v[j]) * scsh[k] + scsh[128 + k], 0.f));
                }
            }
            *(bf16x8*)&smem[0][row][col8] = hv;
            *(bf16x8*)&smem[1][row][col8] = av;
        }
        __syncthreads();
#pragma unroll
        for (int ks2 = 0; ks2 < 2; ks2++) {
            int ko = ks2 * 32 + quad * 8;
            bfrag ah0 = *(const bfrag*)&smem[0][m0w + l16][ko];
            bfrag ah1 = *(const bfrag*)&smem[0][m0w + 16 + l16][ko];
            bfrag aa0 = *(const bfrag*)&smem[1][m0w + l16][ko];
            bfrag aa1 = *(const bfrag*)&smem[1][m0w + 16 + l16][ko];
            int kg = kc + ks2 * 32 + quad * 8;
#pragma unroll
            for (int ct = 0; ct < 8; ct++) {
                bfrag bs  = *(const bfrag*)&Wst[(ct * 16 + l16) * 128 + kg];
                bfrag bnf = *(const bfrag*)&Wnt[(ct * 16 + l16) * 128 + kg];
                acc[0][ct] = __builtin_amdgcn_mfma_f32_16x16x32_bf16(ah0, bs,  acc[0][ct], 0, 0, 0);
                acc[0][ct] = __builtin_amdgcn_mfma_f32_16x16x32_bf16(aa0, bnf, acc[0][ct], 0, 0, 0);
                acc[1][ct] = __builtin_amdgcn_mfma_f32_16x16x32_bf16(ah1, bs,  acc[1][ct], 0, 0, 0);
                acc[1][ct] = __builtin_amdgcn_mfma_f32_16x16x32_bf16(aa1, bnf, acc[1][ct], 0, 0, 0);
            }
        }
        __syncthreads();
    }

    bf16 (*sout)[136] = (bf16(*)[136])&smem[0][0][0];
    float psum[8], psq[8];
#pragma unroll
    for (int ct = 0; ct < 8; ct++) {
        float bv = bias[ct * 16 + l16];
        float s = 0.f, s2 = 0.f;
#pragma unroll
        for (int rt = 0; rt < 2; rt++) {
#pragma unroll
            for (int r = 0; r < 4; r++) {
                int lrow = m0w + rt * 16 + quad * 4 + r;
                float v = fmaxf(acc[rt][ct][r] + bv, 0.f);
                sout[lrow][ct * 16 + l16] = f2b(v);
                if (row0 + lrow < NN) { s += v; s2 += v * v; }
            }
        }
        psum[ct] = s; psq[ct] = s2;
    }
#pragma unroll
    for (int ct = 0; ct < 8; ct++) {
        psum[ct] += __shfl_xor(psum[ct], 16); psum[ct] += __shfl_xor(psum[ct], 32);
        psq[ct]  += __shfl_xor(psq[ct], 16);  psq[ct]  += __shfl_xor(psq[ct], 32);
    }
    if (lane < 16) {
#pragma unroll
        for (int ct = 0; ct < 8; ct++) {
            atomicAdd(&sredsum[ct * 16 + lane], psum[ct]);
            atomicAdd(&sredsq[ct * 16 + lane],  psq[ct]);
        }
    }
    __syncthreads();
#pragma unroll
    for (int i = 0; i < 8; i++) {
        int f = i * 256 + t;
        int row = f >> 4;
        int c16 = f & 15;
        int grow = row0 + row;
        if (grow < NN) {
            bf16x8 ov = *(const bf16x8*)&sout[row][c16 * 8];
            *(bf16x8*)&outp[(size_t)grow * 128 + c16 * 8] = ov;
            if (outf8) {
                *(uint2*)&outf8[(size_t)grow * 128 + c16 * 8] =
                    pk8_fp8(b2f(ov.v[0]), b2f(ov.v[1]), b2f(ov.v[2]), b2f(ov.v[3]),
                            b2f(ov.v[4]), b2f(ov.v[5]), b2f(ov.v[6]), b2f(ov.v[7]));
            }
        }
    }
    if (t < 128) {
        atomicAdd(&bnsums[t], sredsum[t]);
        atomicAdd(&bnsums[128 + t], sredsq[t]);
    }
}

__global__ void k_bn_fin(const float* __restrict__ sums, const float* __restrict__ g,
                         const float* __restrict__ be, float* __restrict__ scsh)
{
    int t = threadIdx.x;
    if (t < 128) {
        float mu = sums[t] / (float)NN;
        float var = sums[128 + t] / (float)NN - mu * mu;
        float sc = g[t] * rsqrtf(var + BN_EPS);
        scsh[t] = sc;
        scsh[128 + t] = be[t] - mu * sc;
    }
}

// ---------------- layer-2 reduction (vectorized) ----------------
__global__ __launch_bounds__(256) void k_l2_reduce(const bf16* __restrict__ h, const float* __restrict__ scsh,
                                                   const float* __restrict__ wsrc, float* __restrict__ ue)
{
    __shared__ float su[128], se[128];
    int t = threadIdx.x;
    if (t < 128) { su[t] = 0.f; se[t] = 0.f; }
    __syncthreads();
    int c0 = (t & 15) * 8;
    int rof = t >> 4;
    float sc[8], sh[8];
#pragma unroll
    for (int j = 0; j < 8; j++) { sc[j] = scsh[c0 + j]; sh[j] = scsh[128 + c0 + j]; }
    float u[8], es[8];
#pragma unroll
    for (int j = 0; j < 8; j++) { u[j] = 0.f; es[j] = 0.f; }
    int rpb = (NN + gridDim.x - 1) / gridDim.x;
    int r0 = blockIdx.x * rpb;
    int r1 = min(r0 + rpb, NN);
    for (int r = r0 + rof; r < r1; r += 16) {
        bf16x8 v = *(const bf16x8*)&h[(size_t)r * 128 + c0];
        float w = wsrc[r];
#pragma unroll
        for (int j = 0; j < 8; j++) {
            float x = fmaxf(b2f(v.v[j]) * sc[j] + sh[j], 0.f);
            u[j] += x; es[j] += w * x;
        }
    }
#pragma unroll
    for (int j = 0; j < 8; j++) { atomicAdd(&su[c0 + j], u[j]); atomicAdd(&se[c0 + j], es[j]); }
    __syncthreads();
    if (t < 128) { atomicAdd(&ue[t], su[t]); atomicAdd(&ue[128 + t], se[t]); }
}

__global__ void k_final(const float* __restrict__ ue, const float* __restrict__ Ws2,
                        const float* __restrict__ Wn2, const float* __restrict__ b2,
                        float* __restrict__ out)
{
    __shared__ float logit[32];
    int t = threadIdx.x;
    const float inv = 1.0f / (float)NN;
    if (t < 32) {
        float acc = b2[t];
        for (int k = 0; k < 128; k++)
            acc += (ue[k] * inv) * Ws2[k * 32 + t] + (ue[128 + k] * inv) * Wn2[k * 32 + t];
        logit[t] = acc;
    }
    __syncthreads();
    if (t < 32) {
        float m = -1e30f;
        for (int j = 0; j < 32; j++) m = fmaxf(m, logit[j]);
        float s = 0.f;
        for (int j = 0; j < 32; j++) s += expf(logit[j] - m);
        out[t] = expf(logit[t] - m) / s;
    }
}

extern "C" void kernel_launch(void* const* d_in, const int* in_sizes, int n_in,
                              void* d_out, int out_size, void* d_ws, size_t ws_size,
                              hipStream_t stream)
{
    const float* feat = (const float*)d_in[0];
    const int*   src  = (const int*)d_in[1];
    const int*   dst  = (const int*)d_in[2];
    const float* Ws0  = (const float*)d_in[3];
    const float* Wn0  = (const float*)d_in[4];
    const float* b0   = (const float*)d_in[5];
    const float* Ws1  = (const float*)d_in[6];
    const float* Wn1  = (const float*)d_in[7];
    const float* b1   = (const float*)d_in[8];
    const float* Ws2  = (const float*)d_in[9];
    const float* Wn2  = (const float*)d_in[10];
    const float* b2   = (const float*)d_in[11];
    const float* g0   = (const float*)d_in[12];
    const float* be0  = (const float*)d_in[13];
    const float* g1   = (const float*)d_in[14];
    const float* be1  = (const float*)d_in[15];

    char* p = (char*)d_ws;
    auto alloc = [&](size_t b) -> void* {
        void* r = (void*)p;
        p += (b + 255) & ~(size_t)255;
        return r;
    };
    bf16* BB     = (bf16*)alloc((size_t)NN * 128 * 2);   // featbf -> h0 (in-place)
    bf16* A      = (bf16*)alloc((size_t)NN * 128 * 2);   // pairsD alias -> agg0 -> agg1 -> h1
    unsigned char* F8 = (unsigned char*)alloc((size_t)NN * 128); // fp8 feat -> fp8 h0
    unsigned* packS = (unsigned*)alloc((size_t)NE * 4);  // src-sorted packed; esrc aliases it
    int*  offs   = (int*)alloc((size_t)(NN + 1) * 4);
    float* invd  = (float*)alloc((size_t)NN * 4);
    float* wsrc  = (float*)alloc((size_t)NN * 4);
    float* bn0   = (float*)alloc(256 * 4);
    float* scsh0 = (float*)alloc(256 * 4);
    float* bn1   = (float*)alloc(256 * 4);
    float* scsh1 = (float*)alloc(256 * 4);
    float* ue    = (float*)alloc(256 * 4);
    bf16* Ws0t   = (bf16*)alloc(16384 * 2);
    bf16* Wn0t   = (bf16*)alloc(16384 * 2);
    bf16* Ws1t   = (bf16*)alloc(16384 * 2);
    bf16* Wn1t   = (bf16*)alloc(16384 * 2);
    int*  bucketCountD = (int*)alloc((NBUCK + 1) * 4);
    int*  bucketStartD = (int*)alloc((NBUCK + 1) * 4);
    int*  blockBaseD   = (int*)alloc((size_t)ABLK * NBUCK * 4);
    int*  bucketCountS = (int*)alloc((NBUCK + 1) * 4);
    int*  bucketStartS = (int*)alloc((NBUCK + 1) * 4);
    int*  blockBaseS   = (int*)alloc((size_t)ABLK * NBUCK * 4);

    // pairsD aliases A (12.8MB <= 25.6MB): A dead until first k_aggregate (after k_pb2).
    uint2* pairsD = (uint2*)A;
    // esrc aliases packS (both NE*4): packS dead after k_wsrc2; k_pb2 writes esrc after.
    int* esrc = (int*)packS;

    hipMemsetAsync(bucketCountD, 0, (NBUCK + 1) * 4, stream);
    hipMemsetAsync(bucketCountS, 0, (NBUCK + 1) * 4, stream);
    hipMemsetAsync(bn0, 0, 256 * 4, stream);
    hipMemsetAsync(bn1, 0, 256 * 4, stream);
    hipMemsetAsync(ue, 0, 256 * 4, stream);

    const int GB = (NN + GM - 1) / GM;

    k_convert<<<(NN * 128) / (256 * 8), 256, 0, stream>>>(feat, BB, F8, NN * 128);
    k_wtrans<<<256, 256, 0, stream>>>(Ws0, Wn0, Ws1, Wn1, Ws0t, Wn0t, Ws1t, Wn1t);

    // ---- CSR build: dual bucketed counting sort (dst for esrc/offs, src for wsrc) ----
    k_pa1<<<ABLK, 256, 0, stream>>>(dst, src, bucketCountD, blockBaseD, bucketCountS, blockBaseS);
    k_bscan2<<<2, 512, 0, stream>>>(bucketCountD, bucketStartD, bucketCountS, bucketStartS);
    k_pa2<<<ABLK, 256, 0, stream>>>(src, dst, bucketStartD, blockBaseD, bucketStartS, blockBaseS, pairsD, packS);
    k_pb1<<<NBUCK, 256, 0, stream>>>(pairsD, bucketStartD, offs, invd);
    k_wsrc2<<<NBUCK, 256, 0, stream>>>(packS, bucketStartS, invd, wsrc);    // last read of packS
    k_pb2<<<NBUCK, 256, 0, stream>>>(pairsD, offs, esrc);                   // esrc overwrites packS region

    // ---- layer 0 ----
    k_aggregate<<<(NN + 3) / 4, 256, 0, stream>>>(F8, A, offs, esrc, invd, nullptr, 0);
    k_gemm_mfma<<<GB, 256, 0, stream>>>(BB, A, Ws0t, Wn0t, b0, nullptr, 0, BB, F8, bn0);  // F8 := fp8(h0)
    k_bn_fin<<<1, 128, 0, stream>>>(bn0, g0, be0, scsh0);

    // ---- layer 1 ----
    k_aggregate<<<(NN + 3) / 4, 256, 0, stream>>>(F8, A, offs, esrc, invd, scsh0, 1);
    k_gemm_mfma<<<GB, 256, 0, stream>>>(BB, A, Ws1t, Wn1t, b1, scsh0, 1, A, nullptr, bn1);
    k_bn_fin<<<1, 128, 0, stream>>>(bn1, g1, be1, scsh1);

    // ---- layer 2 (collapsed to column reductions) ----
    k_l2_reduce<<<256, 256, 0, stream>>>(A, scsh1, wsrc, ue);
    k_final<<<1, 64, 0, stream>>>(ue, Ws2, Wn2, b2, (float*)d_out);
}

// Round 12
// 481.314 us; speedup vs baseline: 1.1294x; 1.0361x over previous
//
#include <hip/hip_runtime.h>
#include <hip/hip_bf16.h>

typedef __hip_bfloat16 bf16;
typedef __hip_bfloat162 bf162;

#define NN 100000
#define NE 1600000
#define BN_EPS 1e-5f

// bucketed CSR build
#define BSH 8
#define NBUCK ((NN + 255) >> BSH)      // 391
#define ABLK 128
#define EPBA ((NE + ABLK - 1) / ABLK)  // 12500
#define CAP 6144                       // staging capacity (mean bucket = 4096)

struct alignas(16) bf16x8 { bf16 v[8]; };

typedef __bf16 bfrag __attribute__((ext_vector_type(8)));
typedef float f4 __attribute__((ext_vector_type(4)));
typedef float f2 __attribute__((ext_vector_type(2)));

static __device__ __forceinline__ float b2f(bf16 x){ return __bfloat162float(x); }
static __device__ __forceinline__ bf16 f2b(float x){ return __float2bfloat16(x); }

// pack 8 fp32 -> 8 fp8(e4m3, hw OCP on gfx950) as uint2
static __device__ __forceinline__ uint2 pk8_fp8(float x0,float x1,float x2,float x3,
                                                float x4,float x5,float x6,float x7)
{
    int lo = __builtin_amdgcn_cvt_pk_fp8_f32(x0, x1, 0, 0);
    lo = __builtin_amdgcn_cvt_pk_fp8_f32(x2, x3, lo, 1);
    int hi = __builtin_amdgcn_cvt_pk_fp8_f32(x4, x5, 0, 0);
    hi = __builtin_amdgcn_cvt_pk_fp8_f32(x6, x7, hi, 1);
    return make_uint2((unsigned)lo, (unsigned)hi);
}

// ---------------- fp32 -> fp8 convert (bf16 copy no longer needed) ----------------
__global__ __launch_bounds__(256) void k_convert(const float* __restrict__ in,
                                                 unsigned char* __restrict__ outf8, int n)
{
    int i = (blockIdx.x * 256 + threadIdx.x) * 8;
    if (i + 7 < n) {
        float4 a = *(const float4*)(in + i);
        float4 b = *(const float4*)(in + i + 4);
        *(uint2*)(outf8 + i) = pk8_fp8(a.x,a.y,a.z,a.w,b.x,b.y,b.z,b.w);
    }
}

// ---------------- weight transpose+convert: Wt[n][k] = bf16(W[k][n]) ----------------
__global__ __launch_bounds__(256) void k_wtrans(const float* __restrict__ W0, const float* __restrict__ W1,
                                                const float* __restrict__ W2, const float* __restrict__ W3,
                                                bf16* __restrict__ T0, bf16* __restrict__ T1,
                                                bf16* __restrict__ T2, bf16* __restrict__ T3)
{
    int m = blockIdx.x >> 6;
    int t = (blockIdx.x & 63) * 256 + threadIdx.x;
    const float* W = (m == 0) ? W0 : (m == 1) ? W1 : (m == 2) ? W2 : W3;
    bf16* T = (m == 0) ? T0 : (m == 1) ? T1 : (m == 2) ? T2 : T3;
    int n = t >> 7, k = t & 127;
    T[n * 128 + k] = f2b(W[k * 128 + n]);
}

// ---------------- pass A1: per-block bucket histograms for BOTH dst and src ----------------
__global__ __launch_bounds__(256) void k_pa1(const int* __restrict__ dst, const int* __restrict__ src,
                                             int* __restrict__ bucketCountD, int* __restrict__ blockBaseD,
                                             int* __restrict__ bucketCountS, int* __restrict__ blockBaseS)
{
    __shared__ int histD[NBUCK];
    __shared__ int histS[NBUCK];
    int t = threadIdx.x;
    for (int i = t; i < NBUCK; i += 256) { histD[i] = 0; histS[i] = 0; }
    __syncthreads();
    int e0 = blockIdx.x * EPBA, e1 = min(e0 + EPBA, NE);
    for (int e = e0 + t; e < e1; e += 256) {
        unsigned bd = ((unsigned)dst[e]) >> BSH;
        unsigned bs = ((unsigned)src[e]) >> BSH;
        if (bd < (unsigned)NBUCK) atomicAdd(&histD[bd], 1);
        if (bs < (unsigned)NBUCK) atomicAdd(&histS[bs], 1);
    }
    __syncthreads();
    for (int i = t; i < NBUCK; i += 256) {
        blockBaseD[blockIdx.x * NBUCK + i] = atomicAdd(&bucketCountD[i], histD[i]);
        blockBaseS[blockIdx.x * NBUCK + i] = atomicAdd(&bucketCountS[i], histS[i]);
    }
}

// ---------------- bucket scan x2 (391 -> exclusive), block 0 = D, block 1 = S ----------------
__global__ __launch_bounds__(512) void k_bscan2(const int* __restrict__ cntD, int* __restrict__ startD,
                                                const int* __restrict__ cntS, int* __restrict__ startS)
{
    __shared__ int sd[512];
    const int* cnt = (blockIdx.x == 0) ? cntD : cntS;
    int* start = (blockIdx.x == 0) ? startD : startS;
    int t = threadIdx.x;
    int v = (t < NBUCK) ? cnt[t] : 0;
    sd[t] = v;
    __syncthreads();
    for (int o = 1; o < 512; o <<= 1) {
        int x = (t >= o) ? sd[t - o] : 0;
        __syncthreads();
        sd[t] += x;
        __syncthreads();
    }
    if (t < NBUCK) start[t] = sd[t] - v;
    if (t == 0) start[NBUCK] = NE;
}

// ---------------- pass A2: scatter packD (dst-bucketed, (dst&255)<<24|src) + packS ((src&255)<<24|dst) ----------------
__global__ __launch_bounds__(256) void k_pa2(const int* __restrict__ src, const int* __restrict__ dst,
                                             const int* __restrict__ bucketStartD, const int* __restrict__ blockBaseD,
                                             const int* __restrict__ bucketStartS, const int* __restrict__ blockBaseS,
                                             unsigned* __restrict__ packD, unsigned* __restrict__ packS)
{
    __shared__ int baseD[NBUCK];
    __shared__ int curD[NBUCK];
    __shared__ int baseS[NBUCK];
    __shared__ int curS[NBUCK];
    int t = threadIdx.x;
    for (int i = t; i < NBUCK; i += 256) {
        baseD[i] = bucketStartD[i] + blockBaseD[blockIdx.x * NBUCK + i];
        curD[i] = 0;
        baseS[i] = bucketStartS[i] + blockBaseS[blockIdx.x * NBUCK + i];
        curS[i] = 0;
    }
    __syncthreads();
    int e0 = blockIdx.x * EPBA, e1 = min(e0 + EPBA, NE);
    for (int e = e0 + t; e < e1; e += 256) {
        int s = src[e], d = dst[e];
        unsigned bd = ((unsigned)d) >> BSH;
        if (bd < (unsigned)NBUCK) {
            int r = atomicAdd(&curD[bd], 1);
            unsigned idx = (unsigned)(baseD[bd] + r);
            if (idx < (unsigned)NE)
                packD[idx] = (((unsigned)d & 255u) << 24) | ((unsigned)s & 0xFFFFFFu);
        }
        unsigned bs = ((unsigned)s) >> BSH;
        if (bs < (unsigned)NBUCK) {
            int r = atomicAdd(&curS[bs], 1);
            unsigned idx = (unsigned)(baseS[bs] + r);
            if (idx < (unsigned)NE)
                packS[idx] = (((unsigned)s & 255u) << 24) | ((unsigned)d & 0xFFFFFFu);
        }
    }
}

// ---------------- fused pass B: degree hist + scan -> offs/invd, then in-bucket sort -> esrc ----------------
__global__ __launch_bounds__(256) void k_pbD(const unsigned* __restrict__ packD, const int* __restrict__ bucketStartD,
                                             int* __restrict__ offs, float* __restrict__ invd,
                                             int* __restrict__ esrc)
{
    __shared__ int dcnt[256];
    __shared__ int sscan[256];
    __shared__ int cur[256];
    __shared__ int S[CAP];
    int t = threadIdx.x;
    int b = blockIdx.x;
    int base = b << BSH;
    dcnt[t] = 0;
    cur[t] = 0;
    for (int i = t; i < CAP; i += 256) S[i] = 0;
    __syncthreads();
    int p0 = bucketStartD[b], p1 = bucketStartD[b + 1];
    int cnt = p1 - p0;
    for (int i = p0 + t; i < p1; i += 256)
        atomicAdd(&dcnt[packD[i] >> 24], 1);
    __syncthreads();
    int my = dcnt[t];
    sscan[t] = my;
    __syncthreads();
    for (int o = 1; o < 256; o <<= 1) {
        int v = (t >= o) ? sscan[t - o] : 0;
        __syncthreads();
        sscan[t] += v;
        __syncthreads();
    }
    int lo = sscan[t] - my;   // exclusive in-bucket offset
    if (base + t < NN) {
        offs[base + t] = p0 + lo;
        invd[base + t] = 1.0f / (float)max(my, 1);
    }
    if (b == NBUCK - 1 && t == 0) offs[NN] = NE;
    __syncthreads();
    sscan[t] = lo;            // repurpose as loffs
    __syncthreads();
    if (cnt <= CAP) {
        for (int i = p0 + t; i < p1; i += 256) {
            unsigned v = packD[i];
            unsigned li = v >> 24;
            int pos = sscan[li] + atomicAdd(&cur[li], 1);
            if ((unsigned)pos >= (unsigned)cnt) pos = cnt - 1;
            S[pos] = (int)(v & 0xFFFFFFu);
        }
        __syncthreads();
        for (int i = t; i < cnt; i += 256) esrc[p0 + i] = S[i];
    } else {
        for (int i = p0 + t; i < p1; i += 256) {
            unsigned v = packD[i];
            unsigned li = v >> 24;
            int pos = sscan[li] + atomicAdd(&cur[li], 1);
            if ((unsigned)pos >= (unsigned)cnt) pos = cnt - 1;
            esrc[p0 + pos] = (int)(v & 0xFFFFFFu);
        }
    }
}

// ---------------- wsrc via src-buckets: LDS accumulate, coalesced write, zero global atomics ----------------
__global__ __launch_bounds__(256) void k_wsrc2(const unsigned* __restrict__ packS, const int* __restrict__ bucketStartS,
                                               const float* __restrict__ invd, float* __restrict__ wsrc)
{
    __shared__ float wacc[256];
    int t = threadIdx.x;
    wacc[t] = 0.f;
    __syncthreads();
    int b = blockIdx.x;
    int base = b << BSH;
    int p0 = bucketStartS[b], p1 = bucketStartS[b + 1];
    for (int i = p0 + t; i < p1; i += 256) {
        unsigned v = packS[i];
        unsigned li = v >> 24;
        unsigned dy = v & 0xFFFFFFu;
        if (dy >= (unsigned)NN) dy = 0u;
        atomicAdd(&wacc[li], invd[dy]);
    }
    __syncthreads();
    if (base + t < NN) wsrc[base + t] = wacc[t];
}

// ---------------- mean aggregation from fp8 rows: 1 wave/node, 4 edge-slots x 16 lanes x 8B ----------------
// Winning round-11 structure: 4 independent gathers in flight + masked-chunk tail.
__global__ __launch_bounds__(256) void k_aggregate(const unsigned char* __restrict__ inf8, bf16* __restrict__ out,
                                                   const int* __restrict__ offs, const int* __restrict__ esrc,
                                                   const float* __restrict__ invd,
                                                   const float* __restrict__ scsh, int use_ss)
{
    int row = blockIdx.x * 4 + (threadIdx.x >> 6);
    if (row >= NN) return;
    int lane = threadIdx.x & 63;
    int grp = lane >> 4;
    int c0 = (lane & 15) * 8;
    float sc[8], sh[8];
    if (use_ss) {
#pragma unroll
        for (int j = 0; j < 8; j++) { sc[j] = scsh[c0 + j]; sh[j] = scsh[128 + c0 + j]; }
    }
    int e0 = offs[row], e1 = offs[row + 1];
    float a[8];
#pragma unroll
    for (int j = 0; j < 8; j++) a[j] = 0.f;

    auto unpack = [&](uint2 u, float* v) {
        f2 p0 = __builtin_amdgcn_cvt_pk_f32_fp8(u.x, 0);
        f2 p1 = __builtin_amdgcn_cvt_pk_f32_fp8(u.x, 1);
        f2 p2 = __builtin_amdgcn_cvt_pk_f32_fp8(u.y, 0);
        f2 p3 = __builtin_amdgcn_cvt_pk_f32_fp8(u.y, 1);
        v[0]=p0.x; v[1]=p0.y; v[2]=p1.x; v[3]=p1.y; v[4]=p2.x; v[5]=p2.y; v[6]=p3.x; v[7]=p3.y;
    };

    int e = e0 + grp;
    for (; e + 12 < e1; e += 16) {
        int s0 = esrc[e], s1 = esrc[e + 4], s2 = esrc[e + 8], s3 = esrc[e + 12];
        uint2 u0 = *(const uint2*)&inf8[(size_t)s0 * 128 + c0];
        uint2 u1 = *(const uint2*)&inf8[(size_t)s1 * 128 + c0];
        uint2 u2 = *(const uint2*)&inf8[(size_t)s2 * 128 + c0];
        uint2 u3 = *(const uint2*)&inf8[(size_t)s3 * 128 + c0];
        float v0[8], v1[8], v2[8], v3[8];
        unpack(u0, v0); unpack(u1, v1); unpack(u2, v2); unpack(u3, v3);
        if (use_ss) {
#pragma unroll
            for (int j = 0; j < 8; j++)
                a[j] += fmaxf(v0[j] * sc[j] + sh[j], 0.f) + fmaxf(v1[j] * sc[j] + sh[j], 0.f)
                      + fmaxf(v2[j] * sc[j] + sh[j], 0.f) + fmaxf(v3[j] * sc[j] + sh[j], 0.f);
        } else {
#pragma unroll
            for (int j = 0; j < 8; j++)
                a[j] += (v0[j] + v1[j]) + (v2[j] + v3[j]);
        }
    }
    if (e < e1) {
        int i1 = e + 4, i2 = e + 8;
        float m1 = (i1 < e1) ? 1.f : 0.f;
        float m2 = (i2 < e1) ? 1.f : 0.f;
        if (i1 >= e1) i1 = e;
        if (i2 >= e1) i2 = e;
        int s0 = esrc[e], s1 = esrc[i1], s2 = esrc[i2];
        uint2 u0 = *(const uint2*)&inf8[(size_t)s0 * 128 + c0];
        uint2 u1 = *(const uint2*)&inf8[(size_t)s1 * 128 + c0];
        uint2 u2 = *(const uint2*)&inf8[(size_t)s2 * 128 + c0];
        float v0[8], v1[8], v2[8];
        unpack(u0, v0); unpack(u1, v1); unpack(u2, v2);
        if (use_ss) {
#pragma unroll
            for (int j = 0; j < 8; j++)
                a[j] += fmaxf(v0[j] * sc[j] + sh[j], 0.f)
                      + m1 * fmaxf(v1[j] * sc[j] + sh[j], 0.f)
                      + m2 * fmaxf(v2[j] * sc[j] + sh[j], 0.f);
        } else {
#pragma unroll
            for (int j = 0; j < 8; j++)
                a[j] += v0[j] + m1 * v1[j] + m2 * v2[j];
        }
    }
#pragma unroll
    for (int j = 0; j < 8; j++) {
        a[j] += __shfl_xor(a[j], 16);
        a[j] += __shfl_xor(a[j], 32);
    }
    if (grp == 0) {
        float id = invd[row];
        bf16x8 o;
#pragma unroll
        for (int j = 0; j < 8; j++) o.v[j] = f2b(a[j] * id);
        *(bf16x8*)&out[(size_t)row * 128 + c0] = o;
    }
}

// ---------------- MFMA dual GEMM: out = relu(T(Hs)@Ws + Ag@Wn + b); Hs from fp32 or fp8; fused BN stats ----------------
#define GM 128
__global__ __launch_bounds__(256) void k_gemm_mfma(const void* __restrict__ HsSrc, int hs_fp8,
                                                   const bf16* __restrict__ Ag,
                                                   const bf16* __restrict__ Wst, const bf16* __restrict__ Wnt,
                                                   const float* __restrict__ bias,
                                                   const float* __restrict__ scsh, int use_ss,
                                                   bf16* __restrict__ outp, unsigned char* __restrict__ outf8,
                                                   float* __restrict__ bnsums)
{
    __shared__ bf16 smem[2][128][72];
    __shared__ float sredsum[128], sredsq[128];
    int t = threadIdx.x;
    int row0 = blockIdx.x * GM;
    int lane = t & 63;
    int l16 = lane & 15;
    int quad = lane >> 4;
    int m0w = (t >> 6) * 32;

    if (t < 128) { sredsum[t] = 0.f; sredsq[t] = 0.f; }

    f4 acc[2][8];
#pragma unroll
    for (int rt = 0; rt < 2; rt++)
#pragma unroll
        for (int ct = 0; ct < 8; ct++) { f4 z = {0.f, 0.f, 0.f, 0.f}; acc[rt][ct] = z; }

    for (int kc = 0; kc < 128; kc += 64) {
#pragma unroll
        for (int i = 0; i < 4; i++) {
            int f = i * 256 + t;
            int row = f >> 3;
            int col8 = (f & 7) * 8;
            int grow = row0 + row;
            float hv32[8];
            bf16x8 av;
            if (grow < NN) {
                if (hs_fp8) {
                    uint2 u = *(const uint2*)((const unsigned char*)HsSrc + (size_t)grow * 128 + kc + col8);
                    f2 q0 = __builtin_amdgcn_cvt_pk_f32_fp8(u.x, 0);
                    f2 q1 = __builtin_amdgcn_cvt_pk_f32_fp8(u.x, 1);
                    f2 q2 = __builtin_amdgcn_cvt_pk_f32_fp8(u.y, 0);
                    f2 q3 = __builtin_amdgcn_cvt_pk_f32_fp8(u.y, 1);
                    hv32[0]=q0.x; hv32[1]=q0.y; hv32[2]=q1.x; hv32[3]=q1.y;
                    hv32[4]=q2.x; hv32[5]=q2.y; hv32[6]=q3.x; hv32[7]=q3.y;
                } else {
                    const float* fp = (const float*)HsSrc + (size_t)grow * 128 + kc + col8;
                    float4 x = *(const float4*)fp;
                    float4 y = *(const float4*)(fp + 4);
                    hv32[0]=x.x; hv32[1]=x.y; hv32[2]=x.z; hv32[3]=x.w;
                    hv32[4]=y.x; hv32[5]=y.y; hv32[6]=y.z; hv32[7]=y.w;
                }
                av = *(const bf16x8*)&Ag[(size_t)grow * 128 + kc + col8];
            } else {
#pragma unroll
                for (int j = 0; j < 8; j++) { hv32[j] = 0.f; av.v[j] = f2b(0.f); }
            }
            if (use_ss) {
#pragma unroll
                for (int j = 0; j < 8; j++) {
                    int k = kc + col8 + j;
                    hv32[j] = fmaxf(hv32[j] * scsh[k] + scsh[128 + k], 0.f);
                }
            }
            bf16x8 hv;
#pragma unroll
            for (int j = 0; j < 8; j++) hv.v[j] = f2b(hv32[j]);
            *(bf16x8*)&smem[0][row][col8] = hv;
            *(bf16x8*)&smem[1][row][col8] = av;
        }
        __syncthreads();
#pragma unroll
        for (int ks2 = 0; ks2 < 2; ks2++) {
            int ko = ks2 * 32 + quad * 8;
            bfrag ah0 = *(const bfrag*)&smem[0][m0w + l16][ko];
            bfrag ah1 = *(const bfrag*)&smem[0][m0w + 16 + l16][ko];
            bfrag aa0 = *(const bfrag*)&smem[1][m0w + l16][ko];
            bfrag aa1 = *(const bfrag*)&smem[1][m0w + 16 + l16][ko];
            int kg = kc + ks2 * 32 + quad * 8;
#pragma unroll
            for (int ct = 0; ct < 8; ct++) {
                bfrag bs  = *(const bfrag*)&Wst[(ct * 16 + l16) * 128 + kg];
                bfrag bnf = *(const bfrag*)&Wnt[(ct * 16 + l16) * 128 + kg];
                acc[0][ct] = __builtin_amdgcn_mfma_f32_16x16x32_bf16(ah0, bs,  acc[0][ct], 0, 0, 0);
                acc[0][ct] = __builtin_amdgcn_mfma_f32_16x16x32_bf16(aa0, bnf, acc[0][ct], 0, 0, 0);
                acc[1][ct] = __builtin_amdgcn_mfma_f32_16x16x32_bf16(ah1, bs,  acc[1][ct], 0, 0, 0);
                acc[1][ct] = __builtin_amdgcn_mfma_f32_16x16x32_bf16(aa1, bnf, acc[1][ct], 0, 0, 0);
            }
        }
        __syncthreads();
    }

    bf16 (*sout)[136] = (bf16(*)[136])&smem[0][0][0];
    float psum[8], psq[8];
#pragma unroll
    for (int ct = 0; ct < 8; ct++) {
        float bv = bias[ct * 16 + l16];
        float s = 0.f, s2 = 0.f;
#pragma unroll
        for (int rt = 0; rt < 2; rt++) {
#pragma unroll
            for (int r = 0; r < 4; r++) {
                int lrow = m0w + rt * 16 + quad * 4 + r;
                float v = fmaxf(acc[rt][ct][r] + bv, 0.f);
                sout[lrow][ct * 16 + l16] = f2b(v);
                if (row0 + lrow < NN) { s += v; s2 += v * v; }
            }
        }
        psum[ct] = s; psq[ct] = s2;
    }
#pragma unroll
    for (int ct = 0; ct < 8; ct++) {
        psum[ct] += __shfl_xor(psum[ct], 16); psum[ct] += __shfl_xor(psum[ct], 32);
        psq[ct]  += __shfl_xor(psq[ct], 16);  psq[ct]  += __shfl_xor(psq[ct], 32);
    }
    if (lane < 16) {
#pragma unroll
        for (int ct = 0; ct < 8; ct++) {
            atomicAdd(&sredsum[ct * 16 + lane], psum[ct]);
            atomicAdd(&sredsq[ct * 16 + lane],  psq[ct]);
        }
    }
    __syncthreads();
#pragma unroll
    for (int i = 0; i < 8; i++) {
        int f = i * 256 + t;
        int row = f >> 4;
        int c16 = f & 15;
        int grow = row0 + row;
        if (grow < NN) {
            bf16x8 ov = *(const bf16x8*)&sout[row][c16 * 8];
            if (outp) *(bf16x8*)&outp[(size_t)grow * 128 + c16 * 8] = ov;
            if (outf8) {
                *(uint2*)&outf8[(size_t)grow * 128 + c16 * 8] =
                    pk8_fp8(b2f(ov.v[0]), b2f(ov.v[1]), b2f(ov.v[2]), b2f(ov.v[3]),
                            b2f(ov.v[4]), b2f(ov.v[5]), b2f(ov.v[6]), b2f(ov.v[7]));
            }
        }
    }
    if (t < 128) {
        atomicAdd(&bnsums[t], sredsum[t]);
        atomicAdd(&bnsums[128 + t], sredsq[t]);
    }
}

__global__ void k_bn_fin(const float* __restrict__ sums, const float* __restrict__ g,
                         const float* __restrict__ be, float* __restrict__ scsh)
{
    int t = threadIdx.x;
    if (t < 128) {
        float mu = sums[t] / (float)NN;
        float var = sums[128 + t] / (float)NN - mu * mu;
        float sc = g[t] * rsqrtf(var + BN_EPS);
        scsh[t] = sc;
        scsh[128 + t] = be[t] - mu * sc;
    }
}

// ---------------- layer-2 reduction (vectorized) ----------------
__global__ __launch_bounds__(256) void k_l2_reduce(const bf16* __restrict__ h, const float* __restrict__ scsh,
                                                   const float* __restrict__ wsrc, float* __restrict__ ue)
{
    __shared__ float su[128], se[128];
    int t = threadIdx.x;
    if (t < 128) { su[t] = 0.f; se[t] = 0.f; }
    __syncthreads();
    int c0 = (t & 15) * 8;
    int rof = t >> 4;
    float sc[8], sh[8];
#pragma unroll
    for (int j = 0; j < 8; j++) { sc[j] = scsh[c0 + j]; sh[j] = scsh[128 + c0 + j]; }
    float u[8], es[8];
#pragma unroll
    for (int j = 0; j < 8; j++) { u[j] = 0.f; es[j] = 0.f; }
    int rpb = (NN + gridDim.x - 1) / gridDim.x;
    int r0 = blockIdx.x * rpb;
    int r1 = min(r0 + rpb, NN);
    for (int r = r0 + rof; r < r1; r += 16) {
        bf16x8 v = *(const bf16x8*)&h[(size_t)r * 128 + c0];
        float w = wsrc[r];
#pragma unroll
        for (int j = 0; j < 8; j++) {
            float x = fmaxf(b2f(v.v[j]) * sc[j] + sh[j], 0.f);
            u[j] += x; es[j] += w * x;
        }
    }
#pragma unroll
    for (int j = 0; j < 8; j++) { atomicAdd(&su[c0 + j], u[j]); atomicAdd(&se[c0 + j], es[j]); }
    __syncthreads();
    if (t < 128) { atomicAdd(&ue[t], su[t]); atomicAdd(&ue[128 + t], se[t]); }
}

__global__ void k_final(const float* __restrict__ ue, const float* __restrict__ Ws2,
                        const float* __restrict__ Wn2, const float* __restrict__ b2,
                        float* __restrict__ out)
{
    __shared__ float logit[32];
    int t = threadIdx.x;
    const float inv = 1.0f / (float)NN;
    if (t < 32) {
        float acc = b2[t];
        for (int k = 0; k < 128; k++)
            acc += (ue[k] * inv) * Ws2[k * 32 + t] + (ue[128 + k] * inv) * Wn2[k * 32 + t];
        logit[t] = acc;
    }
    __syncthreads();
    if (t < 32) {
        float m = -1e30f;
        for (int j = 0; j < 32; j++) m = fmaxf(m, logit[j]);
        float s = 0.f;
        for (int j = 0; j < 32; j++) s += expf(logit[j] - m);
        out[t] = expf(logit[t] - m) / s;
    }
}

extern "C" void kernel_launch(void* const* d_in, const int* in_sizes, int n_in,
                              void* d_out, int out_size, void* d_ws, size_t ws_size,
                              hipStream_t stream)
{
    const float* feat = (const float*)d_in[0];
    const int*   src  = (const int*)d_in[1];
    const int*   dst  = (const int*)d_in[2];
    const float* Ws0  = (const float*)d_in[3];
    const float* Wn0  = (const float*)d_in[4];
    const float* b0   = (const float*)d_in[5];
    const float* Ws1  = (const float*)d_in[6];
    const float* Wn1  = (const float*)d_in[7];
    const float* b1   = (const float*)d_in[8];
    const float* Ws2  = (const float*)d_in[9];
    const float* Wn2  = (const float*)d_in[10];
    const float* b2   = (const float*)d_in[11];
    const float* g0   = (const float*)d_in[12];
    const float* be0  = (const float*)d_in[13];
    const float* g1   = (const float*)d_in[14];
    const float* be1  = (const float*)d_in[15];

    char* p = (char*)d_ws;
    auto alloc = [&](size_t b) -> void* {
        void* r = (void*)p;
        p += (b + 255) & ~(size_t)255;
        return r;
    };
    bf16* A      = (bf16*)alloc((size_t)NN * 128 * 2);   // packD alias -> agg0 -> agg1 -> h1
    unsigned char* F8 = (unsigned char*)alloc((size_t)NN * 128); // fp8 feat -> fp8 h0
    unsigned* packS = (unsigned*)alloc((size_t)NE * 4);  // src-sorted packed
    int*  esrc   = (int*)alloc((size_t)NE * 4);          // own buffer now (no aliasing)
    int*  offs   = (int*)alloc((size_t)(NN + 1) * 4);
    float* invd  = (float*)alloc((size_t)NN * 4);
    float* wsrc  = (float*)alloc((size_t)NN * 4);
    // ---- contiguous zero-region (single memset) ----
    char* zstart = p;
    int*  bucketCountD = (int*)alloc((NBUCK + 1) * 4);
    int*  bucketCountS = (int*)alloc((NBUCK + 1) * 4);
    float* bn0   = (float*)alloc(256 * 4);
    float* bn1   = (float*)alloc(256 * 4);
    float* ue    = (float*)alloc(256 * 4);
    size_t zlen = (size_t)(p - zstart);
    // ------------------------------------------------
    float* scsh0 = (float*)alloc(256 * 4);
    float* scsh1 = (float*)alloc(256 * 4);
    bf16* Ws0t   = (bf16*)alloc(16384 * 2);
    bf16* Wn0t   = (bf16*)alloc(16384 * 2);
    bf16* Ws1t   = (bf16*)alloc(16384 * 2);
    bf16* Wn1t   = (bf16*)alloc(16384 * 2);
    int*  bucketStartD = (int*)alloc((NBUCK + 1) * 4);
    int*  bucketStartS = (int*)alloc((NBUCK + 1) * 4);
    int*  blockBaseD   = (int*)alloc((size_t)ABLK * NBUCK * 4);
    int*  blockBaseS   = (int*)alloc((size_t)ABLK * NBUCK * 4);

    // packD aliases A (6.4MB <= 25.6MB): A dead until first k_aggregate (after k_pbD).
    unsigned* packD = (unsigned*)A;

    hipMemsetAsync(zstart, 0, zlen, stream);

    const int GB = (NN + GM - 1) / GM;

    k_convert<<<(NN * 128) / (256 * 8), 256, 0, stream>>>(feat, F8, NN * 128);
    k_wtrans<<<256, 256, 0, stream>>>(Ws0, Wn0, Ws1, Wn1, Ws0t, Wn0t, Ws1t, Wn1t);

    // ---- CSR build: dual bucketed counting sort (dst for esrc/offs, src for wsrc) ----
    k_pa1<<<ABLK, 256, 0, stream>>>(dst, src, bucketCountD, blockBaseD, bucketCountS, blockBaseS);
    k_bscan2<<<2, 512, 0, stream>>>(bucketCountD, bucketStartD, bucketCountS, bucketStartS);
    k_pa2<<<ABLK, 256, 0, stream>>>(src, dst, bucketStartD, blockBaseD, bucketStartS, blockBaseS, packD, packS);
    k_pbD<<<NBUCK, 256, 0, stream>>>(packD, bucketStartD, offs, invd, esrc);   // last read of packD
    k_wsrc2<<<NBUCK, 256, 0, stream>>>(packS, bucketStartS, invd, wsrc);

    // ---- layer 0 ----
    k_aggregate<<<(NN + 3) / 4, 256, 0, stream>>>(F8, A, offs, esrc, invd, nullptr, 0);
    k_gemm_mfma<<<GB, 256, 0, stream>>>(feat, 0, A, Ws0t, Wn0t, b0, nullptr, 0, nullptr, F8, bn0);  // F8 := fp8(h0)
    k_bn_fin<<<1, 128, 0, stream>>>(bn0, g0, be0, scsh0);

    // ---- layer 1 ----
    k_aggregate<<<(NN + 3) / 4, 256, 0, stream>>>(F8, A, offs, esrc, invd, scsh0, 1);
    k_gemm_mfma<<<GB, 256, 0, stream>>>(F8, 1, A, Ws1t, Wn1t, b1, scsh0, 1, A, nullptr, bn1);       // A := h1
    k_bn_fin<<<1, 128, 0, stream>>>(bn1, g1, be1, scsh1);

    // ---- layer 2 (collapsed to column reductions) ----
    k_l2_reduce<<<256, 256, 0, stream>>>(A, scsh1, wsrc, ue);
    k_final<<<1, 64, 0, stream>>>(ue, Ws2, Wn2, b2, (float*)d_out);
}